// Round 20
// baseline (274.869 us; speedup 1.0000x reference)
//
#include <hip/hip_runtime.h>

// SpatialAttention (QKNorm, no 1/sqrt(d)): B=1,T=8,S=1024,HID=1152,H=16,D=72
// Pipeline: fused pre (cvt x->bf16 sigma + W^T bf16 sigma) | qkv GEMM (256x128, vt LDS
//           transpose) | rmsnorm k (vectorized) | flash attn (fused q-RMSNorm, 2 groups,
//           fused QK, shared-V fused PV, exact skip-rescale, cvt_pk, LDS-staged O-store) |
//           out GEMM (256x128) -> f32
// sigma = swap bits 2<->3 of k within each 16-k block on BOTH operands (k-sum invariant).

typedef __attribute__((ext_vector_type(4))) short s16x4;
typedef __attribute__((ext_vector_type(8))) short s16x8;
typedef __attribute__((ext_vector_type(4))) float f32x4;
typedef __attribute__((ext_vector_type(16))) float f32x16;
typedef __attribute__((ext_vector_type(4))) int i32x4;

__device__ __forceinline__ unsigned short f2b(float x) {
  unsigned u = __float_as_uint(x);
  u += 0x7FFFu + ((u >> 16) & 1u);
  return (unsigned short)(u >> 16);
}
__device__ __forceinline__ float b2f(unsigned short u) {
  return __uint_as_float(((unsigned)u) << 16);
}
__device__ __forceinline__ void gld16(const void* g, void* l) {
  __builtin_amdgcn_global_load_lds(
      (const __attribute__((address_space(1))) void*)g,
      (__attribute__((address_space(3))) void*)l, 16, 0, 0);
}

// ---------------- fused pre: x->bf16 (blocks 0..2303) + W^T (blocks 2304..7487) ----------
__global__ __launch_bounds__(256) void pre_kernel(
    const float* __restrict__ x, const float* __restrict__ Wq,
    const float* __restrict__ Wkv, const float* __restrict__ Wo,
    unsigned short* __restrict__ xb, unsigned short* __restrict__ WqT,
    unsigned short* __restrict__ WkvT, unsigned short* __restrict__ WoT) {
  constexpr int K = 1152;
  int id = blockIdx.x;
  if (id < 2304) {
    int i = id * 256 + threadIdx.x;
    const float4* p = (const float4*)(x + (size_t)i * 16);
    float4 a = p[0], b = p[1], c = p[2], d = p[3];
    s16x8 r0, r1;
    r0[0] = (short)f2b(a.x); r0[1] = (short)f2b(a.y); r0[2] = (short)f2b(a.z); r0[3] = (short)f2b(a.w);
    r0[4] = (short)f2b(c.x); r0[5] = (short)f2b(c.y); r0[6] = (short)f2b(c.z); r0[7] = (short)f2b(c.w);
    r1[0] = (short)f2b(b.x); r1[1] = (short)f2b(b.y); r1[2] = (short)f2b(b.z); r1[3] = (short)f2b(b.w);
    r1[4] = (short)f2b(d.x); r1[5] = (short)f2b(d.y); r1[6] = (short)f2b(d.z); r1[7] = (short)f2b(d.w);
    *(s16x8*)(xb + (size_t)i * 16) = r0;
    *(s16x8*)(xb + (size_t)i * 16 + 8) = r1;
    return;
  }
  id -= 2304;
  const float* W;
  unsigned short* WT;
  int N;
  if (id < 1296) { W = Wq; WT = WqT; N = 1152; }
  else if (id < 3888) { W = Wkv; WT = WkvT; N = 2304; id -= 1296; }
  else { W = Wo; WT = WoT; N = 1152; id -= 3888; }
  int ntiles = N / 32;
  int bxx = id % ntiles, byy = id / ntiles;
  __shared__ float tile[32][33];
  int n0 = bxx * 32, k0 = byy * 32;
  int tx = threadIdx.x & 31, ty = threadIdx.x >> 5;
#pragma unroll
  for (int i = 0; i < 4; i++)
    tile[ty + i * 8][tx] = W[(size_t)(k0 + ty + i * 8) * N + n0 + tx];
  __syncthreads();
  int stx = (tx & 19) | ((tx & 4) << 1) | ((tx & 8) >> 1);  // swap bits 2,3
#pragma unroll
  for (int i = 0; i < 4; i++)
    WT[(size_t)(n0 + ty + i * 8) * K + k0 + stx] = f2b(tile[tx][ty + i * 8]);
}

// ---------------- fused qkv GEMM: [8192,1152] @ [3456,1152]^T ----------------
__global__ __launch_bounds__(256) void gemm_qkv_kernel(const unsigned short* __restrict__ A,
                                                       const unsigned short* __restrict__ BT,
                                                       const float* __restrict__ biasq,
                                                       const float* __restrict__ biaskv,
                                                       unsigned short* __restrict__ qn,
                                                       unsigned short* __restrict__ kn,
                                                       unsigned short* __restrict__ vt) {
  constexpr int K = 1152;
  constexpr int NT = K / 32;  // 36
  __shared__ __align__(16) unsigned short LDSU[3 * 8192 + 3 * 4096];  // 72 KB
  unsigned short* As = LDSU;
  unsigned short* Bs = LDSU + 3 * 8192;
  int tid = threadIdx.x;
  int lane = tid & 63, wave = tid >> 6;
  int wr = (wave >> 1) * 128, wc = (wave & 1) * 64;
  int l31 = lane & 31, lh = lane >> 5;
  int bid = blockIdx.x;
  int xcd = bid & 7;
  int w = bid >> 3;
  int st = w / 12, inner = w - st * 12;
  int ibx = inner % 3, iby = inner / 3;
  int bx = st * 3 + ibx;
  int by = xcd * 4 + iby;
  int brow = by * 256, bcol = bx * 128;
  const unsigned short* AsrcP[4];
  const unsigned short* BsrcP[2];
  int dstA[4], dstB[2];
#pragma unroll
  for (int i = 0; i < 4; i++) {
    int c = tid + 256 * i;
    int row = c >> 2, j = c & 3;
    AsrcP[i] = A + (size_t)(brow + row) * K + (j ^ ((row >> 1) & 3)) * 8;
    dstA[i] = (wave * 64 + 256 * i) * 8;
  }
#pragma unroll
  for (int i = 0; i < 2; i++) {
    int c = tid + 256 * i;
    int row = c >> 2, j = c & 3;
    BsrcP[i] = BT + (size_t)(bcol + row) * K + (j ^ ((row >> 1) & 3)) * 8;
    dstB[i] = (wave * 64 + 256 * i) * 8;
  }
#define STAGE(KT, BUF)                                           \
  {                                                              \
    int kb = (KT) * 32;                                          \
    gld16(AsrcP[0] + kb, &As[(BUF) * 8192 + dstA[0]]);           \
    gld16(AsrcP[1] + kb, &As[(BUF) * 8192 + dstA[1]]);           \
    gld16(AsrcP[2] + kb, &As[(BUF) * 8192 + dstA[2]]);           \
    gld16(AsrcP[3] + kb, &As[(BUF) * 8192 + dstA[3]]);           \
    gld16(BsrcP[0] + kb, &Bs[(BUF) * 4096 + dstB[0]]);           \
    gld16(BsrcP[1] + kb, &Bs[(BUF) * 4096 + dstB[1]]);           \
  }
  int fr = (l31 >> 1) & 3;
  int slotk[2] = {(lh ^ fr) * 8, ((2 + lh) ^ fr) * 8};
  STAGE(0, 0);
  STAGE(1, 1);
  f32x16 acc[4][2] = {};
  int cur = 0;
  for (int kt = 0; kt < NT; kt++) {
    if (kt < NT - 1)
      asm volatile("s_waitcnt vmcnt(6)\n\ts_barrier" ::: "memory");
    else
      asm volatile("s_waitcnt vmcnt(0)\n\ts_barrier" ::: "memory");
    if (kt + 2 < NT) {
      int nb = (cur == 0) ? 2 : cur - 1;
      STAGE(kt + 2, nb);
    }
    int ab = cur * 8192, bb = cur * 4096;
#pragma unroll
    for (int kk = 0; kk < 2; kk++) {
      int so = slotk[kk];
      s16x8 af[4], bf[2];
#pragma unroll
      for (int m = 0; m < 4; m++)
        af[m] = *(const s16x8*)&As[ab + (wr + m * 32 + l31) * 32 + so];
#pragma unroll
      for (int n = 0; n < 2; n++)
        bf[n] = *(const s16x8*)&Bs[bb + (wc + n * 32 + l31) * 32 + so];
      __builtin_amdgcn_s_setprio(1);
#pragma unroll
      for (int m = 0; m < 4; m++)
#pragma unroll
        for (int n = 0; n < 2; n++)
          acc[m][n] = __builtin_amdgcn_mfma_f32_32x32x16_bf16(af[m], bf[n], acc[m][n], 0, 0, 0);
      __builtin_amdgcn_s_setprio(0);
    }
    cur = (cur == 2) ? 0 : cur + 1;
  }
#undef STAGE
  if (bcol >= 2304) {
    __syncthreads();
    int c0 = bcol - 2304;
#pragma unroll
    for (int m = 0; m < 4; m++) {
#pragma unroll
      for (int n = 0; n < 2; n++) {
        int col = wc + n * 32 + l31;
        float bias = biaskv[1152 + c0 + col];
#pragma unroll
        for (int reg = 0; reg < 16; reg++) {
          int row = wr + m * 32 + (reg & 3) + 8 * (reg >> 2) + 4 * lh;
          LDSU[col * 264 + row] = f2b(acc[m][n][reg] + bias);
        }
      }
    }
    __syncthreads();
    int t = brow >> 10, sbase = brow & 1023;
#pragma unroll
    for (int i = 0; i < 16; i++) {
      int id = tid + 256 * i;
      int col = id >> 5, rowc = id & 31;
      int c = c0 + col;
      int h = c / 72, d = c - h * 72;
      s16x8 v8 = *(const s16x8*)&LDSU[col * 264 + rowc * 8];
      *(s16x8*)(vt + ((size_t)((t * 16 + h) * 80 + d)) * 1024 + sbase + rowc * 8) = v8;
    }
  } else {
#pragma unroll
    for (int m = 0; m < 4; m++) {
#pragma unroll
      for (int n = 0; n < 2; n++) {
        int gcol = bcol + wc + n * 32 + l31;
        float bias = (gcol < 1152) ? biasq[gcol] : biaskv[gcol - 1152];
        int c = (gcol < 1152) ? gcol : gcol - 1152;
        int h = c / 72, d = c - h * 72;
        unsigned short* dst = (gcol < 1152) ? qn : kn;
#pragma unroll
        for (int reg = 0; reg < 16; reg++) {
          int grow = brow + wr + m * 32 + (reg & 3) + 8 * (reg >> 2) + 4 * lh;
          float v = acc[m][n][reg] + bias;
          int t = grow >> 10, s = grow & 1023;
          dst[((size_t)((t * 16 + h) * 1024 + s)) * 96 + d] = f2b(v);
        }
      }
    }
  }
}

// ---------------- out GEMM (256x128): out = att @ WoT^T, f32 ----------------
__global__ __launch_bounds__(256) void gemm_out_kernel(const unsigned short* __restrict__ A,
                                                       const unsigned short* __restrict__ BT,
                                                       float* __restrict__ outF) {
  constexpr int K = 1152;
  constexpr int NT = K / 32;
  __shared__ __align__(16) unsigned short As[3 * 8192];
  __shared__ __align__(16) unsigned short Bs[3 * 4096];
  int tid = threadIdx.x;
  int lane = tid & 63, wave = tid >> 6;
  int wr = (wave >> 1) * 128, wc = (wave & 1) * 64;
  int l31 = lane & 31, lh = lane >> 5;
  int bid = blockIdx.x;
  int xcd = bid & 7;
  int w = bid >> 3;
  int iby = w / 9, bx = w - iby * 9;
  int by = xcd * 4 + iby;
  int brow = by * 256, bcol = bx * 128;
  const unsigned short* AsrcP[4];
  const unsigned short* BsrcP[2];
  int dstA[4], dstB[2];
#pragma unroll
  for (int i = 0; i < 4; i++) {
    int c = tid + 256 * i;
    int row = c >> 2, j = c & 3;
    AsrcP[i] = A + (size_t)(brow + row) * K + (j ^ ((row >> 1) & 3)) * 8;
    dstA[i] = (wave * 64 + 256 * i) * 8;
  }
#pragma unroll
  for (int i = 0; i < 2; i++) {
    int c = tid + 256 * i;
    int row = c >> 2, j = c & 3;
    BsrcP[i] = BT + (size_t)(bcol + row) * K + (j ^ ((row >> 1) & 3)) * 8;
    dstB[i] = (wave * 64 + 256 * i) * 8;
  }
#define STAGE(KT, BUF)                                           \
  {                                                              \
    int kb = (KT) * 32;                                          \
    gld16(AsrcP[0] + kb, &As[(BUF) * 8192 + dstA[0]]);           \
    gld16(AsrcP[1] + kb, &As[(BUF) * 8192 + dstA[1]]);           \
    gld16(AsrcP[2] + kb, &As[(BUF) * 8192 + dstA[2]]);           \
    gld16(AsrcP[3] + kb, &As[(BUF) * 8192 + dstA[3]]);           \
    gld16(BsrcP[0] + kb, &Bs[(BUF) * 4096 + dstB[0]]);           \
    gld16(BsrcP[1] + kb, &Bs[(BUF) * 4096 + dstB[1]]);           \
  }
  int fr = (l31 >> 1) & 3;
  int slotk[2] = {(lh ^ fr) * 8, ((2 + lh) ^ fr) * 8};
  STAGE(0, 0);
  STAGE(1, 1);
  f32x16 acc[4][2] = {};
  int cur = 0;
  for (int kt = 0; kt < NT; kt++) {
    if (kt < NT - 1)
      asm volatile("s_waitcnt vmcnt(6)\n\ts_barrier" ::: "memory");
    else
      asm volatile("s_waitcnt vmcnt(0)\n\ts_barrier" ::: "memory");
    if (kt + 2 < NT) {
      int nb = (cur == 0) ? 2 : cur - 1;
      STAGE(kt + 2, nb);
    }
    int ab = cur * 8192, bb = cur * 4096;
#pragma unroll
    for (int kk = 0; kk < 2; kk++) {
      int so = slotk[kk];
      s16x8 af[4], bf[2];
#pragma unroll
      for (int m = 0; m < 4; m++)
        af[m] = *(const s16x8*)&As[ab + (wr + m * 32 + l31) * 32 + so];
#pragma unroll
      for (int n = 0; n < 2; n++)
        bf[n] = *(const s16x8*)&Bs[bb + (wc + n * 32 + l31) * 32 + so];
      __builtin_amdgcn_s_setprio(1);
#pragma unroll
      for (int m = 0; m < 4; m++)
#pragma unroll
        for (int n = 0; n < 2; n++)
          acc[m][n] = __builtin_amdgcn_mfma_f32_32x32x16_bf16(af[m], bf[n], acc[m][n], 0, 0, 0);
      __builtin_amdgcn_s_setprio(0);
    }
    cur = (cur == 2) ? 0 : cur + 1;
  }
#undef STAGE
#pragma unroll
  for (int m = 0; m < 4; m++) {
#pragma unroll
    for (int n = 0; n < 2; n++) {
#pragma unroll
      for (int reg = 0; reg < 16; reg++) {
        int grow = brow + wr + m * 32 + (reg & 3) + 8 * (reg >> 2) + 4 * lh;
        int gcol = bcol + wc + n * 32 + l31;
        outF[(size_t)grow * 1152 + gcol] = acc[m][n][reg];
      }
    }
  }
}

// ---------------- vectorized K RMSNorm: 16-lane group per row, s16x8 loads ----------------
__global__ __launch_bounds__(256) void rmsnorm_k_kernel(unsigned short* __restrict__ kn,
                                                        const float* __restrict__ kg) {
  int row = blockIdx.x * 16 + (threadIdx.x >> 4);
  int g16 = threadIdx.x & 15;
  int h = (row >> 10) & 15;
  size_t base = (size_t)row * 96;
  s16x8 v8 = {};
  float vv[8];
  float ss = 0.f;
  if (g16 < 12) {
    v8 = *(const s16x8*)(kn + base + g16 * 8);
#pragma unroll
    for (int j = 0; j < 8; j++) {
      vv[j] = b2f((unsigned short)v8[j]);
      if (g16 < 9) ss += vv[j] * vv[j];
    }
  }
  ss += __shfl_xor(ss, 1);
  ss += __shfl_xor(ss, 2);
  ss += __shfl_xor(ss, 4);
  ss += __shfl_xor(ss, 8);
  float sc = rsqrtf(ss * (1.0f / 72.0f) + 1e-6f);
  if (g16 < 12) {
    s16x8 r;
    if (g16 < 9) {
#pragma unroll
      for (int j = 0; j < 8; j++) r[j] = (short)f2b(vv[j] * sc * kg[h * 72 + g16 * 8 + j]);
    } else {
#pragma unroll
      for (int j = 0; j < 8; j++) r[j] = 0;
    }
    *(s16x8*)(kn + base + g16 * 8) = r;
  }
}

// ---------------- flash attention: fused q-RMSNorm, 128 q-rows/block, fused-QK,
//                  shared-V fused PV, single-buffer V, exact skip-rescale, cvt_pk,
//                  LDS-staged coalesced O-store ----------------
__global__ __launch_bounds__(256) void attn_kernel(const unsigned short* __restrict__ Qn,
                                                   const unsigned short* __restrict__ Kn,
                                                   const unsigned short* __restrict__ VtG,
                                                   const float* __restrict__ qg,
                                                   unsigned short* __restrict__ att) {
  __shared__ unsigned short Kl[2][64][100];
  __shared__ unsigned short Vt[80][76];
  int tid = threadIdx.x;
  int lane = tid & 63, wave = tid >> 6;
  int l15 = lane & 15, lq = lane >> 4, kf = lq * 4;
  int bid = blockIdx.x;
  int orig = (bid & 7) * 128 + (bid >> 3);
  int qb = orig & 7, th = orig >> 3;
  int t = th >> 4, h = th & 15;
  const unsigned short* Q = Qn + (size_t)th * 1024 * 96;
  const unsigned short* Kp = Kn + (size_t)th * 1024 * 96;
  const unsigned short* Vg = VtG + (size_t)th * 80 * 1024;
  const float* qgam = qg + h * 72;
  int qrow0 = qb * 128 + wave * 32;
  int krow[3], kco[3], vd[3], vco[3];
#pragma unroll
  for (int i = 0; i < 3; i++) {
    int c = tid + i * 256;
    krow[i] = c / 12;
    kco[i] = c - 12 * krow[i];
    int cc = tid + i * 256;
    vd[i] = cc >> 3;
    vco[i] = cc & 7;
  }
  bool v2 = tid < 128;
  s16x8 sk[3], sv[3];
  // ---- Q load with FUSED q-RMSNorm (masked ss over d<72; pads forced to 0) ----
  s16x8 qf[2][3];
#pragma unroll
  for (int g = 0; g < 2; g++) {
    float rv[3][8];
    float ss = 0.f, ss2 = 0.f;
#pragma unroll
    for (int c = 0; c < 3; c++) {
      const unsigned short* p = Q + (size_t)(qrow0 + g * 16 + l15) * 96 + c * 32 + kf;
      s16x4 lo = *(const s16x4*)p;
      s16x4 hi = *(const s16x4*)(p + 16);
#pragma unroll
      for (int j = 0; j < 8; j++) {
        unsigned short u = (unsigned short)(j < 4 ? lo[j] : hi[j - 4]);
        float v = b2f(u);
        rv[c][j] = v;
        if (c < 2) ss += v * v;
        else if (j < 4) ss2 += v * v;
      }
    }
    ss += (lq < 2) ? ss2 : 0.f;
    ss += __shfl_xor(ss, 16);
    ss += __shfl_xor(ss, 32);
    float sc = rsqrtf(ss * (1.0f / 72.0f) + 1e-6f);
#pragma unroll
    for (int c = 0; c < 3; c++) {
      float vv[8];
#pragma unroll
      for (int j = 0; j < 8; j++) {
        int d = c * 32 + 4 * lq + (j & 3) + 16 * (j >> 2);
        bool live = (c < 2) || (j < 4 && lq < 2);
        int idx = live ? d : 0;
        float gmv = qgam[idx];
        vv[j] = live ? (rv[c][j] * sc) * gmv : 0.f;
      }
      int w0, w1, w2, w3;
      asm("v_cvt_pk_bf16_f32 %0, %1, %2" : "=v"(w0) : "v"(vv[0]), "v"(vv[1]));
      asm("v_cvt_pk_bf16_f32 %0, %1, %2" : "=v"(w1) : "v"(vv[2]), "v"(vv[3]));
      asm("v_cvt_pk_bf16_f32 %0, %1, %2" : "=v"(w2) : "v"(vv[4]), "v"(vv[5]));
      asm("v_cvt_pk_bf16_f32 %0, %1, %2" : "=v"(w3) : "v"(vv[6]), "v"(vv[7]));
      i32x4 pw = {w0, w1, w2, w3};
      qf[g][c] = __builtin_bit_cast(s16x8, pw);
    }
  }
  f32x4 o[2][5] = {};
  float m_r[2] = {-3.0e38f, -3.0e38f}, l_r[2] = {0.f, 0.f};

  // prologue: tile 0 -> Kl[0], Vt
#pragma unroll
  for (int i = 0; i < 3; i++)
    sk[i] = *(const s16x8*)(Kp + (size_t)krow[i] * 96 + kco[i] * 8);
#pragma unroll
  for (int i = 0; i < 2; i++)
    sv[i] = *(const s16x8*)(Vg + (size_t)vd[i] * 1024 + vco[i] * 8);
  if (v2) sv[2] = *(const s16x8*)(Vg + (size_t)vd[2] * 1024 + vco[2] * 8);
#pragma unroll
  for (int i = 0; i < 3; i++) *(s16x8*)&Kl[0][krow[i]][kco[i] * 8] = sk[i];
#pragma unroll
  for (int i = 0; i < 2; i++) *(s16x8*)&Vt[vd[i]][vco[i] * 8] = sv[i];
  if (v2) *(s16x8*)&Vt[vd[2]][vco[2] * 8] = sv[2];

  for (int tt = 0; tt < 16; tt++) {
    __syncthreads();   // (A) tile tt's Kl[cur]/Vt writes visible
    int cur = tt & 1;
    if (tt < 15) {
      int kv1 = (tt + 1) * 64;
#pragma unroll
      for (int i = 0; i < 3; i++)
        sk[i] = *(const s16x8*)(Kp + (size_t)(kv1 + krow[i]) * 96 + kco[i] * 8);
#pragma unroll
      for (int i = 0; i < 2; i++)
        sv[i] = *(const s16x8*)(Vg + (size_t)vd[i] * 1024 + kv1 + vco[i] * 8);
      if (v2) sv[2] = *(const s16x8*)(Vg + (size_t)vd[2] * 1024 + kv1 + vco[2] * 8);
    }
    // ---- QK^T for BOTH groups, sharing K-fragment reads ----
    f32x4 st0[4], st1[4];
    __builtin_amdgcn_s_setprio(1);
#pragma unroll
    for (int n = 0; n < 4; n++) {
      f32x4 a0 = {}, a1 = {};
#pragma unroll
      for (int c = 0; c < 3; c++) {
        s16x4 lo = *(const s16x4*)&Kl[cur][n * 16 + l15][c * 32 + kf];
        s16x4 hi = *(const s16x4*)&Kl[cur][n * 16 + l15][c * 32 + kf + 16];
        s16x8 kfr = __builtin_shufflevector(lo, hi, 0, 1, 2, 3, 4, 5, 6, 7);
        a0 = __builtin_amdgcn_mfma_f32_16x16x32_bf16(kfr, qf[0][c], a0, 0, 0, 0);
        a1 = __builtin_amdgcn_mfma_f32_16x16x32_bf16(kfr, qf[1][c], a1, 0, 0, 0);
      }
      st0[n] = a0;
      st1[n] = a1;
    }
    __builtin_amdgcn_s_setprio(0);
    // Softmax: tree max (bit-exact reassociation), exact skip-rescale.
#define SOFTMAX(ST, G)                                                        \
    {                                                                         \
      float p8[8];                                                            \
      _Pragma("unroll") for (int j = 0; j < 8; j++)                           \
        p8[j] = fmaxf(ST[j >> 1][(j & 1) * 2], ST[j >> 1][(j & 1) * 2 + 1]);  \
      float p4a = fmaxf(p8[0], p8[1]), p4b = fmaxf(p8[2], p8[3]);             \
      float p4c = fmaxf(p8[4], p8[5]), p4d = fmaxf(p8[6], p8[7]);             \
      float tmax = fmaxf(fmaxf(p4a, p4b), fmaxf(p4c, p4d));                   \
      tmax = fmaxf(tmax, __shfl_xor(tmax, 16));                               \
      tmax = fmaxf(tmax, __shfl_xor(tmax, 32));                               \
      bool up = !__all(tmax <= m_r[G]);                                       \
      float scale = 1.0f;                                                     \
      if (up) {                                                               \
        float mn = fmaxf(m_r[G], tmax);                                       \
        scale = __expf(m_r[G] - mn);                                          \
        m_r[G] = mn;                                                          \
      }                                                                       \
      float sum = 0.f;                                                        \
      _Pragma("unroll") for (int n = 0; n < 4; n++)                           \
        _Pragma("unroll") for (int r = 0; r < 4; r++) {                       \
          float p = __expf(ST[n][r] - m_r[G]);                                \
          ST[n][r] = p;                                                       \
          sum += p;                                                           \
        }                                                                     \
      sum += __shfl_xor(sum, 16);                                             \
      sum += __shfl_xor(sum, 32);                                             \
      if (up) {                                                               \
        l_r[G] = l_r[G] * scale + sum;                                        \
        _Pragma("unroll") for (int r = 0; r < 4; r++) {                       \
          float scq = __shfl(scale, 4 * lq + r);                              \
          _Pragma("unroll") for (int v = 0; v < 5; v++) o[G][v][r] *= scq;    \
        }                                                                     \
      } else {                                                                \
        l_r[G] += sum;                                                        \
      }                                                                       \
    }
    SOFTMAX(st0, 0);
    SOFTMAX(st1, 1);
#undef SOFTMAX
    // ---- fused PV: V fragments read ONCE, feed both groups' accumulators ----
    __builtin_amdgcn_s_setprio(1);
#pragma unroll
    for (int b = 0; b < 2; b++) {
      int a0, a1, a2, a3, b0w, b1w, b2w, b3w;
      asm("v_cvt_pk_bf16_f32 %0, %1, %2" : "=v"(a0) : "v"(st0[2 * b][0]), "v"(st0[2 * b][1]));
      asm("v_cvt_pk_bf16_f32 %0, %1, %2" : "=v"(a1) : "v"(st0[2 * b][2]), "v"(st0[2 * b][3]));
      asm("v_cvt_pk_bf16_f32 %0, %1, %2" : "=v"(a2) : "v"(st0[2 * b + 1][0]), "v"(st0[2 * b + 1][1]));
      asm("v_cvt_pk_bf16_f32 %0, %1, %2" : "=v"(a3) : "v"(st0[2 * b + 1][2]), "v"(st0[2 * b + 1][3]));
      asm("v_cvt_pk_bf16_f32 %0, %1, %2" : "=v"(b0w) : "v"(st1[2 * b][0]), "v"(st1[2 * b][1]));
      asm("v_cvt_pk_bf16_f32 %0, %1, %2" : "=v"(b1w) : "v"(st1[2 * b][2]), "v"(st1[2 * b][3]));
      asm("v_cvt_pk_bf16_f32 %0, %1, %2" : "=v"(b2w) : "v"(st1[2 * b + 1][0]), "v"(st1[2 * b + 1][1]));
      asm("v_cvt_pk_bf16_f32 %0, %1, %2" : "=v"(b3w) : "v"(st1[2 * b + 1][2]), "v"(st1[2 * b + 1][3]));
      i32x4 pw0 = {a0, a1, a2, a3};
      i32x4 pw1 = {b0w, b1w, b2w, b3w};
      s16x8 pf0 = __builtin_bit_cast(s16x8, pw0);
      s16x8 pf1 = __builtin_bit_cast(s16x8, pw1);
#pragma unroll
      for (int v = 0; v < 5; v++) {
        s16x4 vlo = *(const s16x4*)&Vt[v * 16 + l15][b * 32 + kf];
        s16x4 vhi = *(const s16x4*)&Vt[v * 16 + l15][b * 32 + kf + 16];
        s16x8 vf = __builtin_shufflevector(vlo, vhi, 0, 1, 2, 3, 4, 5, 6, 7);
        o[0][v] = __builtin_amdgcn_mfma_f32_16x16x32_bf16(pf0, vf, o[0][v], 0, 0, 0);
        o[1][v] = __builtin_amdgcn_mfma_f32_16x16x32_bf16(pf1, vf, o[1][v], 0, 0, 0);
      }
    }
    __builtin_amdgcn_s_setprio(0);
    if (tt < 15) {
      __syncthreads();  // (B) all waves' PV reads of Vt done
      int nxt = cur ^ 1;
#pragma unroll
      for (int i = 0; i < 3; i++) *(s16x8*)&Kl[nxt][krow[i]][kco[i] * 8] = sk[i];
#pragma unroll
      for (int i = 0; i < 2; i++) *(s16x8*)&Vt[vd[i]][vco[i] * 8] = sv[i];
      if (v2) *(s16x8*)&Vt[vd[2]][vco[2] * 8] = sv[2];
    }
  }
  // ---- epilogue: normalize, stage O through per-wave LDS slice (reuse Kl),
  //      coalesced s16x4 stores (sigma preserves 4-aligned chunks) ----
  __syncthreads();  // all waves done reading Kl (tile 15 QK)
  unsigned short* Osh = (unsigned short*)Kl + wave * 2880;  // 32 rows x 90 u16
#pragma unroll
  for (int g = 0; g < 2; g++)
#pragma unroll
    for (int r = 0; r < 4; r++) {
      float inv = 1.0f / __shfl(l_r[g], 4 * lq + r);
      int lrow = g * 16 + 4 * lq + r;
#pragma unroll
      for (int v = 0; v < 5; v++) {
        if (v < 4 || l15 < 8)
          Osh[lrow * 90 + v * 16 + l15] = f2b(o[g][v][r] * inv);
      }
    }
  // wave reads back only its own slice (in-wave ds ordering via lgkmcnt)
#pragma unroll
  for (int i = 0; i < 9; i++) {
    int id = lane + 64 * i;  // 0..575 = 32 rows x 18 chunks
    int row = id / 18, c4 = id - row * 18;
    int col = h * 72 + c4 * 4;
    int scol = (col & ~12) | ((col & 4) << 1) | ((col & 8) >> 1);
    int qrow = qrow0 + row;
    s16x4 ov = *(const s16x4*)&Osh[row * 90 + c4 * 4];
    *(s16x4*)(att + (size_t)(t * 1024 + qrow) * 1152 + scol) = ov;
  }
}

extern "C" void kernel_launch(void* const* d_in, const int* in_sizes, int n_in,
                              void* d_out, int out_size, void* d_ws, size_t ws_size,
                              hipStream_t stream) {
  const float* x   = (const float*)d_in[0];
  const float* Wq  = (const float*)d_in[1];
  const float* bq  = (const float*)d_in[2];
  const float* Wkv = (const float*)d_in[3];
  const float* bkv = (const float*)d_in[4];
  const float* qg  = (const float*)d_in[5];
  const float* kg  = (const float*)d_in[6];
  const float* Wo  = (const float*)d_in[7];
  float* out = (float*)d_out;

  char* w = (char*)d_ws;
  unsigned short* xb   = (unsigned short*)w; w += (size_t)8192 * 1152 * 2;
  unsigned short* WqT  = (unsigned short*)w; w += (size_t)1152 * 1152 * 2;  // contiguous with WkvT
  unsigned short* WkvT = (unsigned short*)w; w += (size_t)2304 * 1152 * 2;
  unsigned short* WoT  = (unsigned short*)w; w += (size_t)1152 * 1152 * 2;
  unsigned short* qn   = (unsigned short*)w; w += (size_t)128 * 1024 * 96 * 2;
  unsigned short* kn   = (unsigned short*)w; w += (size_t)128 * 1024 * 96 * 2;
  unsigned short* vt   = (unsigned short*)w; w += (size_t)128 * 80 * 1024 * 2;
  unsigned short* att  = (unsigned short*)w; w += (size_t)8192 * 1152 * 2;

  pre_kernel<<<7488, 256, 0, stream>>>(x, Wq, Wkv, Wo, xb, WqT, WkvT, WoT);

  // fused q,k,v^T GEMM: BT = [WqT ; WkvT] = [3456][1152], grid 32*27=864
  gemm_qkv_kernel<<<864, 256, 0, stream>>>(xb, WqT, bq, bkv, qn, kn, vt);
  rmsnorm_k_kernel<<<8192, 256, 0, stream>>>(kn, kg);

  attn_kernel<<<1024, 256, 0, stream>>>(qn, kn, vt, qg, att);

  // out = att @ WoT^T, grid 288 (256x128 blocks)
  gemm_out_kernel<<<288, 256, 0, stream>>>(att, WoT, out);
}

// Round 21
// 269.051 us; speedup vs baseline: 1.0216x; 1.0216x over previous
//
#include <hip/hip_runtime.h>

// SpatialAttention (QKNorm, no 1/sqrt(d)): B=1,T=8,S=1024,HID=1152,H=16,D=72
// Pipeline: fused pre (cvt x->bf16 sigma + W^T bf16 sigma, 1 launch) | qkv GEMM (256x128,
//           vt LDS transpose) | rmsnorm k (vectorized) | flash attn (fused q-RMSNorm,
//           2 groups, fused QK, shared-V fused PV, exact skip-rescale, cvt_pk) |
//           out GEMM (256x128) -> f32
// sigma = swap bits 2<->3 of k within each 16-k block on BOTH operands (k-sum invariant).

typedef __attribute__((ext_vector_type(4))) short s16x4;
typedef __attribute__((ext_vector_type(8))) short s16x8;
typedef __attribute__((ext_vector_type(4))) float f32x4;
typedef __attribute__((ext_vector_type(16))) float f32x16;
typedef __attribute__((ext_vector_type(4))) int i32x4;

__device__ __forceinline__ unsigned short f2b(float x) {
  unsigned u = __float_as_uint(x);
  u += 0x7FFFu + ((u >> 16) & 1u);
  return (unsigned short)(u >> 16);
}
__device__ __forceinline__ float b2f(unsigned short u) {
  return __uint_as_float(((unsigned)u) << 16);
}
__device__ __forceinline__ void gld16(const void* g, void* l) {
  __builtin_amdgcn_global_load_lds(
      (const __attribute__((address_space(1))) void*)g,
      (__attribute__((address_space(3))) void*)l, 16, 0, 0);
}

// ---------------- fused pre: x->bf16 (blocks 0..2303) + W^T (blocks 2304..7487) ----------
__global__ __launch_bounds__(256) void pre_kernel(
    const float* __restrict__ x, const float* __restrict__ Wq,
    const float* __restrict__ Wkv, const float* __restrict__ Wo,
    unsigned short* __restrict__ xb, unsigned short* __restrict__ WqT,
    unsigned short* __restrict__ WkvT, unsigned short* __restrict__ WoT) {
  constexpr int K = 1152;
  int id = blockIdx.x;
  if (id < 2304) {
    int i = id * 256 + threadIdx.x;
    const float4* p = (const float4*)(x + (size_t)i * 16);
    float4 a = p[0], b = p[1], c = p[2], d = p[3];
    s16x8 r0, r1;
    r0[0] = (short)f2b(a.x); r0[1] = (short)f2b(a.y); r0[2] = (short)f2b(a.z); r0[3] = (short)f2b(a.w);
    r0[4] = (short)f2b(c.x); r0[5] = (short)f2b(c.y); r0[6] = (short)f2b(c.z); r0[7] = (short)f2b(c.w);
    r1[0] = (short)f2b(b.x); r1[1] = (short)f2b(b.y); r1[2] = (short)f2b(b.z); r1[3] = (short)f2b(b.w);
    r1[4] = (short)f2b(d.x); r1[5] = (short)f2b(d.y); r1[6] = (short)f2b(d.z); r1[7] = (short)f2b(d.w);
    *(s16x8*)(xb + (size_t)i * 16) = r0;
    *(s16x8*)(xb + (size_t)i * 16 + 8) = r1;
    return;
  }
  id -= 2304;
  const float* W;
  unsigned short* WT;
  int N;
  if (id < 1296) { W = Wq; WT = WqT; N = 1152; }
  else if (id < 3888) { W = Wkv; WT = WkvT; N = 2304; id -= 1296; }
  else { W = Wo; WT = WoT; N = 1152; id -= 3888; }
  int ntiles = N / 32;
  int bxx = id % ntiles, byy = id / ntiles;
  __shared__ float tile[32][33];
  int n0 = bxx * 32, k0 = byy * 32;
  int tx = threadIdx.x & 31, ty = threadIdx.x >> 5;
#pragma unroll
  for (int i = 0; i < 4; i++)
    tile[ty + i * 8][tx] = W[(size_t)(k0 + ty + i * 8) * N + n0 + tx];
  __syncthreads();
  int stx = (tx & 19) | ((tx & 4) << 1) | ((tx & 8) >> 1);  // swap bits 2,3
#pragma unroll
  for (int i = 0; i < 4; i++)
    WT[(size_t)(n0 + ty + i * 8) * K + k0 + stx] = f2b(tile[tx][ty + i * 8]);
}

// ---------------- fused qkv GEMM: [8192,1152] @ [3456,1152]^T ----------------
__global__ __launch_bounds__(256) void gemm_qkv_kernel(const unsigned short* __restrict__ A,
                                                       const unsigned short* __restrict__ BT,
                                                       const float* __restrict__ biasq,
                                                       const float* __restrict__ biaskv,
                                                       unsigned short* __restrict__ qn,
                                                       unsigned short* __restrict__ kn,
                                                       unsigned short* __restrict__ vt) {
  constexpr int K = 1152;
  constexpr int NT = K / 32;  // 36
  __shared__ __align__(16) unsigned short LDSU[3 * 8192 + 3 * 4096];  // 72 KB
  unsigned short* As = LDSU;
  unsigned short* Bs = LDSU + 3 * 8192;
  int tid = threadIdx.x;
  int lane = tid & 63, wave = tid >> 6;
  int wr = (wave >> 1) * 128, wc = (wave & 1) * 64;
  int l31 = lane & 31, lh = lane >> 5;
  int bid = blockIdx.x;
  int xcd = bid & 7;
  int w = bid >> 3;
  int st = w / 12, inner = w - st * 12;
  int ibx = inner % 3, iby = inner / 3;
  int bx = st * 3 + ibx;
  int by = xcd * 4 + iby;
  int brow = by * 256, bcol = bx * 128;
  const unsigned short* AsrcP[4];
  const unsigned short* BsrcP[2];
  int dstA[4], dstB[2];
#pragma unroll
  for (int i = 0; i < 4; i++) {
    int c = tid + 256 * i;
    int row = c >> 2, j = c & 3;
    AsrcP[i] = A + (size_t)(brow + row) * K + (j ^ ((row >> 1) & 3)) * 8;
    dstA[i] = (wave * 64 + 256 * i) * 8;
  }
#pragma unroll
  for (int i = 0; i < 2; i++) {
    int c = tid + 256 * i;
    int row = c >> 2, j = c & 3;
    BsrcP[i] = BT + (size_t)(bcol + row) * K + (j ^ ((row >> 1) & 3)) * 8;
    dstB[i] = (wave * 64 + 256 * i) * 8;
  }
#define STAGE(KT, BUF)                                           \
  {                                                              \
    int kb = (KT) * 32;                                          \
    gld16(AsrcP[0] + kb, &As[(BUF) * 8192 + dstA[0]]);           \
    gld16(AsrcP[1] + kb, &As[(BUF) * 8192 + dstA[1]]);           \
    gld16(AsrcP[2] + kb, &As[(BUF) * 8192 + dstA[2]]);           \
    gld16(AsrcP[3] + kb, &As[(BUF) * 8192 + dstA[3]]);           \
    gld16(BsrcP[0] + kb, &Bs[(BUF) * 4096 + dstB[0]]);           \
    gld16(BsrcP[1] + kb, &Bs[(BUF) * 4096 + dstB[1]]);           \
  }
  int fr = (l31 >> 1) & 3;
  int slotk[2] = {(lh ^ fr) * 8, ((2 + lh) ^ fr) * 8};
  STAGE(0, 0);
  STAGE(1, 1);
  f32x16 acc[4][2] = {};
  int cur = 0;
  for (int kt = 0; kt < NT; kt++) {
    if (kt < NT - 1)
      asm volatile("s_waitcnt vmcnt(6)\n\ts_barrier" ::: "memory");
    else
      asm volatile("s_waitcnt vmcnt(0)\n\ts_barrier" ::: "memory");
    if (kt + 2 < NT) {
      int nb = (cur == 0) ? 2 : cur - 1;
      STAGE(kt + 2, nb);
    }
    int ab = cur * 8192, bb = cur * 4096;
#pragma unroll
    for (int kk = 0; kk < 2; kk++) {
      int so = slotk[kk];
      s16x8 af[4], bf[2];
#pragma unroll
      for (int m = 0; m < 4; m++)
        af[m] = *(const s16x8*)&As[ab + (wr + m * 32 + l31) * 32 + so];
#pragma unroll
      for (int n = 0; n < 2; n++)
        bf[n] = *(const s16x8*)&Bs[bb + (wc + n * 32 + l31) * 32 + so];
      __builtin_amdgcn_s_setprio(1);
#pragma unroll
      for (int m = 0; m < 4; m++)
#pragma unroll
        for (int n = 0; n < 2; n++)
          acc[m][n] = __builtin_amdgcn_mfma_f32_32x32x16_bf16(af[m], bf[n], acc[m][n], 0, 0, 0);
      __builtin_amdgcn_s_setprio(0);
    }
    cur = (cur == 2) ? 0 : cur + 1;
  }
#undef STAGE
  if (bcol >= 2304) {
    __syncthreads();
    int c0 = bcol - 2304;
#pragma unroll
    for (int m = 0; m < 4; m++) {
#pragma unroll
      for (int n = 0; n < 2; n++) {
        int col = wc + n * 32 + l31;
        float bias = biaskv[1152 + c0 + col];
#pragma unroll
        for (int reg = 0; reg < 16; reg++) {
          int row = wr + m * 32 + (reg & 3) + 8 * (reg >> 2) + 4 * lh;
          LDSU[col * 264 + row] = f2b(acc[m][n][reg] + bias);
        }
      }
    }
    __syncthreads();
    int t = brow >> 10, sbase = brow & 1023;
#pragma unroll
    for (int i = 0; i < 16; i++) {
      int id = tid + 256 * i;
      int col = id >> 5, rowc = id & 31;
      int c = c0 + col;
      int h = c / 72, d = c - h * 72;
      s16x8 v8 = *(const s16x8*)&LDSU[col * 264 + rowc * 8];
      *(s16x8*)(vt + ((size_t)((t * 16 + h) * 80 + d)) * 1024 + sbase + rowc * 8) = v8;
    }
  } else {
#pragma unroll
    for (int m = 0; m < 4; m++) {
#pragma unroll
      for (int n = 0; n < 2; n++) {
        int gcol = bcol + wc + n * 32 + l31;
        float bias = (gcol < 1152) ? biasq[gcol] : biaskv[gcol - 1152];
        int c = (gcol < 1152) ? gcol : gcol - 1152;
        int h = c / 72, d = c - h * 72;
        unsigned short* dst = (gcol < 1152) ? qn : kn;
#pragma unroll
        for (int reg = 0; reg < 16; reg++) {
          int grow = brow + wr + m * 32 + (reg & 3) + 8 * (reg >> 2) + 4 * lh;
          float v = acc[m][n][reg] + bias;
          int t = grow >> 10, s = grow & 1023;
          dst[((size_t)((t * 16 + h) * 1024 + s)) * 96 + d] = f2b(v);
        }
      }
    }
  }
}

// ---------------- out GEMM (256x128): out = att @ WoT^T, f32 ----------------
__global__ __launch_bounds__(256) void gemm_out_kernel(const unsigned short* __restrict__ A,
                                                       const unsigned short* __restrict__ BT,
                                                       float* __restrict__ outF) {
  constexpr int K = 1152;
  constexpr int NT = K / 32;
  __shared__ __align__(16) unsigned short As[3 * 8192];
  __shared__ __align__(16) unsigned short Bs[3 * 4096];
  int tid = threadIdx.x;
  int lane = tid & 63, wave = tid >> 6;
  int wr = (wave >> 1) * 128, wc = (wave & 1) * 64;
  int l31 = lane & 31, lh = lane >> 5;
  int bid = blockIdx.x;
  int xcd = bid & 7;
  int w = bid >> 3;
  int iby = w / 9, bx = w - iby * 9;
  int by = xcd * 4 + iby;
  int brow = by * 256, bcol = bx * 128;
  const unsigned short* AsrcP[4];
  const unsigned short* BsrcP[2];
  int dstA[4], dstB[2];
#pragma unroll
  for (int i = 0; i < 4; i++) {
    int c = tid + 256 * i;
    int row = c >> 2, j = c & 3;
    AsrcP[i] = A + (size_t)(brow + row) * K + (j ^ ((row >> 1) & 3)) * 8;
    dstA[i] = (wave * 64 + 256 * i) * 8;
  }
#pragma unroll
  for (int i = 0; i < 2; i++) {
    int c = tid + 256 * i;
    int row = c >> 2, j = c & 3;
    BsrcP[i] = BT + (size_t)(bcol + row) * K + (j ^ ((row >> 1) & 3)) * 8;
    dstB[i] = (wave * 64 + 256 * i) * 8;
  }
#define STAGE(KT, BUF)                                           \
  {                                                              \
    int kb = (KT) * 32;                                          \
    gld16(AsrcP[0] + kb, &As[(BUF) * 8192 + dstA[0]]);           \
    gld16(AsrcP[1] + kb, &As[(BUF) * 8192 + dstA[1]]);           \
    gld16(AsrcP[2] + kb, &As[(BUF) * 8192 + dstA[2]]);           \
    gld16(AsrcP[3] + kb, &As[(BUF) * 8192 + dstA[3]]);           \
    gld16(BsrcP[0] + kb, &Bs[(BUF) * 4096 + dstB[0]]);           \
    gld16(BsrcP[1] + kb, &Bs[(BUF) * 4096 + dstB[1]]);           \
  }
  int fr = (l31 >> 1) & 3;
  int slotk[2] = {(lh ^ fr) * 8, ((2 + lh) ^ fr) * 8};
  STAGE(0, 0);
  STAGE(1, 1);
  f32x16 acc[4][2] = {};
  int cur = 0;
  for (int kt = 0; kt < NT; kt++) {
    if (kt < NT - 1)
      asm volatile("s_waitcnt vmcnt(6)\n\ts_barrier" ::: "memory");
    else
      asm volatile("s_waitcnt vmcnt(0)\n\ts_barrier" ::: "memory");
    if (kt + 2 < NT) {
      int nb = (cur == 0) ? 2 : cur - 1;
      STAGE(kt + 2, nb);
    }
    int ab = cur * 8192, bb = cur * 4096;
#pragma unroll
    for (int kk = 0; kk < 2; kk++) {
      int so = slotk[kk];
      s16x8 af[4], bf[2];
#pragma unroll
      for (int m = 0; m < 4; m++)
        af[m] = *(const s16x8*)&As[ab + (wr + m * 32 + l31) * 32 + so];
#pragma unroll
      for (int n = 0; n < 2; n++)
        bf[n] = *(const s16x8*)&Bs[bb + (wc + n * 32 + l31) * 32 + so];
      __builtin_amdgcn_s_setprio(1);
#pragma unroll
      for (int m = 0; m < 4; m++)
#pragma unroll
        for (int n = 0; n < 2; n++)
          acc[m][n] = __builtin_amdgcn_mfma_f32_32x32x16_bf16(af[m], bf[n], acc[m][n], 0, 0, 0);
      __builtin_amdgcn_s_setprio(0);
    }
    cur = (cur == 2) ? 0 : cur + 1;
  }
#undef STAGE
#pragma unroll
  for (int m = 0; m < 4; m++) {
#pragma unroll
    for (int n = 0; n < 2; n++) {
#pragma unroll
      for (int reg = 0; reg < 16; reg++) {
        int grow = brow + wr + m * 32 + (reg & 3) + 8 * (reg >> 2) + 4 * lh;
        int gcol = bcol + wc + n * 32 + l31;
        outF[(size_t)grow * 1152 + gcol] = acc[m][n][reg];
      }
    }
  }
}

// ---------------- vectorized K RMSNorm: 16-lane group per row, s16x8 loads ----------------
__global__ __launch_bounds__(256) void rmsnorm_k_kernel(unsigned short* __restrict__ kn,
                                                        const float* __restrict__ kg) {
  int row = blockIdx.x * 16 + (threadIdx.x >> 4);
  int g16 = threadIdx.x & 15;
  int h = (row >> 10) & 15;
  size_t base = (size_t)row * 96;
  s16x8 v8 = {};
  float vv[8];
  float ss = 0.f;
  if (g16 < 12) {
    v8 = *(const s16x8*)(kn + base + g16 * 8);
#pragma unroll
    for (int j = 0; j < 8; j++) {
      vv[j] = b2f((unsigned short)v8[j]);
      if (g16 < 9) ss += vv[j] * vv[j];
    }
  }
  ss += __shfl_xor(ss, 1);
  ss += __shfl_xor(ss, 2);
  ss += __shfl_xor(ss, 4);
  ss += __shfl_xor(ss, 8);
  float sc = rsqrtf(ss * (1.0f / 72.0f) + 1e-6f);
  if (g16 < 12) {
    s16x8 r;
    if (g16 < 9) {
#pragma unroll
      for (int j = 0; j < 8; j++) r[j] = (short)f2b(vv[j] * sc * kg[h * 72 + g16 * 8 + j]);
    } else {
#pragma unroll
      for (int j = 0; j < 8; j++) r[j] = 0;
    }
    *(s16x8*)(kn + base + g16 * 8) = r;
  }
}

// ---------------- flash attention: fused q-RMSNorm at Q-load, 128 q-rows/block,
//                  fused-QK both groups, shared-V fused PV, single-buffer V,
//                  exact skip-rescale, cvt_pk ----------------
__global__ __launch_bounds__(256) void attn_kernel(const unsigned short* __restrict__ Qn,
                                                   const unsigned short* __restrict__ Kn,
                                                   const unsigned short* __restrict__ VtG,
                                                   const float* __restrict__ qg,
                                                   unsigned short* __restrict__ att) {
  __shared__ unsigned short Kl[2][64][100];
  __shared__ unsigned short Vt[80][76];
  int tid = threadIdx.x;
  int lane = tid & 63, wave = tid >> 6;
  int l15 = lane & 15, lq = lane >> 4, kf = lq * 4;
  int bid = blockIdx.x;
  int orig = (bid & 7) * 128 + (bid >> 3);
  int qb = orig & 7, th = orig >> 3;
  int t = th >> 4, h = th & 15;
  const unsigned short* Q = Qn + (size_t)th * 1024 * 96;
  const unsigned short* Kp = Kn + (size_t)th * 1024 * 96;
  const unsigned short* Vg = VtG + (size_t)th * 80 * 1024;
  const float* qgam = qg + h * 72;
  int qrow0 = qb * 128 + wave * 32;
  int krow[3], kco[3], vd[3], vco[3];
#pragma unroll
  for (int i = 0; i < 3; i++) {
    int c = tid + i * 256;
    krow[i] = c / 12;
    kco[i] = c - 12 * krow[i];
    int cc = tid + i * 256;
    vd[i] = cc >> 3;
    vco[i] = cc & 7;
  }
  bool v2 = tid < 128;
  s16x8 sk[3], sv[3];
  // ---- Q load with FUSED q-RMSNorm (masked ss over d<72; pads forced to 0) ----
  s16x8 qf[2][3];
#pragma unroll
  for (int g = 0; g < 2; g++) {
    float rv[3][8];
    float ss = 0.f, ss2 = 0.f;
#pragma unroll
    for (int c = 0; c < 3; c++) {
      const unsigned short* p = Q + (size_t)(qrow0 + g * 16 + l15) * 96 + c * 32 + kf;
      s16x4 lo = *(const s16x4*)p;
      s16x4 hi = *(const s16x4*)(p + 16);
#pragma unroll
      for (int j = 0; j < 8; j++) {
        unsigned short u = (unsigned short)(j < 4 ? lo[j] : hi[j - 4]);
        float v = b2f(u);
        rv[c][j] = v;
        if (c < 2) ss += v * v;
        else if (j < 4) ss2 += v * v;
      }
    }
    ss += (lq < 2) ? ss2 : 0.f;
    ss += __shfl_xor(ss, 16);
    ss += __shfl_xor(ss, 32);
    float sc = rsqrtf(ss * (1.0f / 72.0f) + 1e-6f);
#pragma unroll
    for (int c = 0; c < 3; c++) {
      float vv[8];
#pragma unroll
      for (int j = 0; j < 8; j++) {
        int d = c * 32 + 4 * lq + (j & 3) + 16 * (j >> 2);
        bool live = (c < 2) || (j < 4 && lq < 2);
        int idx = live ? d : 0;
        float gmv = qgam[idx];
        vv[j] = live ? (rv[c][j] * sc) * gmv : 0.f;
      }
      int w0, w1, w2, w3;
      asm("v_cvt_pk_bf16_f32 %0, %1, %2" : "=v"(w0) : "v"(vv[0]), "v"(vv[1]));
      asm("v_cvt_pk_bf16_f32 %0, %1, %2" : "=v"(w1) : "v"(vv[2]), "v"(vv[3]));
      asm("v_cvt_pk_bf16_f32 %0, %1, %2" : "=v"(w2) : "v"(vv[4]), "v"(vv[5]));
      asm("v_cvt_pk_bf16_f32 %0, %1, %2" : "=v"(w3) : "v"(vv[6]), "v"(vv[7]));
      i32x4 pw = {w0, w1, w2, w3};
      qf[g][c] = __builtin_bit_cast(s16x8, pw);
    }
  }
  f32x4 o[2][5] = {};
  float m_r[2] = {-3.0e38f, -3.0e38f}, l_r[2] = {0.f, 0.f};

  // prologue: tile 0 -> Kl[0], Vt
#pragma unroll
  for (int i = 0; i < 3; i++)
    sk[i] = *(const s16x8*)(Kp + (size_t)krow[i] * 96 + kco[i] * 8);
#pragma unroll
  for (int i = 0; i < 2; i++)
    sv[i] = *(const s16x8*)(Vg + (size_t)vd[i] * 1024 + vco[i] * 8);
  if (v2) sv[2] = *(const s16x8*)(Vg + (size_t)vd[2] * 1024 + vco[2] * 8);
#pragma unroll
  for (int i = 0; i < 3; i++) *(s16x8*)&Kl[0][krow[i]][kco[i] * 8] = sk[i];
#pragma unroll
  for (int i = 0; i < 2; i++) *(s16x8*)&Vt[vd[i]][vco[i] * 8] = sv[i];
  if (v2) *(s16x8*)&Vt[vd[2]][vco[2] * 8] = sv[2];

  for (int tt = 0; tt < 16; tt++) {
    __syncthreads();   // (A) tile tt's Kl[cur]/Vt writes visible
    int cur = tt & 1;
    if (tt < 15) {
      int kv1 = (tt + 1) * 64;
#pragma unroll
      for (int i = 0; i < 3; i++)
        sk[i] = *(const s16x8*)(Kp + (size_t)(kv1 + krow[i]) * 96 + kco[i] * 8);
#pragma unroll
      for (int i = 0; i < 2; i++)
        sv[i] = *(const s16x8*)(Vg + (size_t)vd[i] * 1024 + kv1 + vco[i] * 8);
      if (v2) sv[2] = *(const s16x8*)(Vg + (size_t)vd[2] * 1024 + kv1 + vco[2] * 8);
    }
    // ---- QK^T for BOTH groups, sharing K-fragment reads ----
    f32x4 st0[4], st1[4];
    __builtin_amdgcn_s_setprio(1);
#pragma unroll
    for (int n = 0; n < 4; n++) {
      f32x4 a0 = {}, a1 = {};
#pragma unroll
      for (int c = 0; c < 3; c++) {
        s16x4 lo = *(const s16x4*)&Kl[cur][n * 16 + l15][c * 32 + kf];
        s16x4 hi = *(const s16x4*)&Kl[cur][n * 16 + l15][c * 32 + kf + 16];
        s16x8 kfr = __builtin_shufflevector(lo, hi, 0, 1, 2, 3, 4, 5, 6, 7);
        a0 = __builtin_amdgcn_mfma_f32_16x16x32_bf16(kfr, qf[0][c], a0, 0, 0, 0);
        a1 = __builtin_amdgcn_mfma_f32_16x16x32_bf16(kfr, qf[1][c], a1, 0, 0, 0);
      }
      st0[n] = a0;
      st1[n] = a1;
    }
    __builtin_amdgcn_s_setprio(0);
#define SOFTMAX(ST, G)                                                        \
    {                                                                         \
      float tmax = ST[0][0];                                                  \
      _Pragma("unroll") for (int n = 0; n < 4; n++)                           \
        _Pragma("unroll") for (int r = 0; r < 4; r++)                         \
          tmax = fmaxf(tmax, ST[n][r]);                                       \
      tmax = fmaxf(tmax, __shfl_xor(tmax, 16));                               \
      tmax = fmaxf(tmax, __shfl_xor(tmax, 32));                               \
      bool up = !__all(tmax <= m_r[G]);                                       \
      float scale = 1.0f;                                                     \
      if (up) {                                                               \
        float mn = fmaxf(m_r[G], tmax);                                       \
        scale = __expf(m_r[G] - mn);                                          \
        m_r[G] = mn;                                                          \
      }                                                                       \
      float sum = 0.f;                                                        \
      _Pragma("unroll") for (int n = 0; n < 4; n++)                           \
        _Pragma("unroll") for (int r = 0; r < 4; r++) {                       \
          float p = __expf(ST[n][r] - m_r[G]);                                \
          ST[n][r] = p;                                                       \
          sum += p;                                                           \
        }                                                                     \
      sum += __shfl_xor(sum, 16);                                             \
      sum += __shfl_xor(sum, 32);                                             \
      if (up) {                                                               \
        l_r[G] = l_r[G] * scale + sum;                                        \
        _Pragma("unroll") for (int r = 0; r < 4; r++) {                       \
          float scq = __shfl(scale, 4 * lq + r);                              \
          _Pragma("unroll") for (int v = 0; v < 5; v++) o[G][v][r] *= scq;    \
        }                                                                     \
      } else {                                                                \
        l_r[G] += sum;                                                        \
      }                                                                       \
    }
    SOFTMAX(st0, 0);
    SOFTMAX(st1, 1);
#undef SOFTMAX
    // ---- fused PV: V fragments read ONCE, feed both groups' accumulators ----
    __builtin_amdgcn_s_setprio(1);
#pragma unroll
    for (int b = 0; b < 2; b++) {
      int a0, a1, a2, a3, b0w, b1w, b2w, b3w;
      asm("v_cvt_pk_bf16_f32 %0, %1, %2" : "=v"(a0) : "v"(st0[2 * b][0]), "v"(st0[2 * b][1]));
      asm("v_cvt_pk_bf16_f32 %0, %1, %2" : "=v"(a1) : "v"(st0[2 * b][2]), "v"(st0[2 * b][3]));
      asm("v_cvt_pk_bf16_f32 %0, %1, %2" : "=v"(a2) : "v"(st0[2 * b + 1][0]), "v"(st0[2 * b + 1][1]));
      asm("v_cvt_pk_bf16_f32 %0, %1, %2" : "=v"(a3) : "v"(st0[2 * b + 1][2]), "v"(st0[2 * b + 1][3]));
      asm("v_cvt_pk_bf16_f32 %0, %1, %2" : "=v"(b0w) : "v"(st1[2 * b][0]), "v"(st1[2 * b][1]));
      asm("v_cvt_pk_bf16_f32 %0, %1, %2" : "=v"(b1w) : "v"(st1[2 * b][2]), "v"(st1[2 * b][3]));
      asm("v_cvt_pk_bf16_f32 %0, %1, %2" : "=v"(b2w) : "v"(st1[2 * b + 1][0]), "v"(st1[2 * b + 1][1]));
      asm("v_cvt_pk_bf16_f32 %0, %1, %2" : "=v"(b3w) : "v"(st1[2 * b + 1][2]), "v"(st1[2 * b + 1][3]));
      i32x4 pw0 = {a0, a1, a2, a3};
      i32x4 pw1 = {b0w, b1w, b2w, b3w};
      s16x8 pf0 = __builtin_bit_cast(s16x8, pw0);
      s16x8 pf1 = __builtin_bit_cast(s16x8, pw1);
#pragma unroll
      for (int v = 0; v < 5; v++) {
        s16x4 vlo = *(const s16x4*)&Vt[v * 16 + l15][b * 32 + kf];
        s16x4 vhi = *(const s16x4*)&Vt[v * 16 + l15][b * 32 + kf + 16];
        s16x8 vf = __builtin_shufflevector(vlo, vhi, 0, 1, 2, 3, 4, 5, 6, 7);
        o[0][v] = __builtin_amdgcn_mfma_f32_16x16x32_bf16(pf0, vf, o[0][v], 0, 0, 0);
        o[1][v] = __builtin_amdgcn_mfma_f32_16x16x32_bf16(pf1, vf, o[1][v], 0, 0, 0);
      }
    }
    __builtin_amdgcn_s_setprio(0);
    if (tt < 15) {
      __syncthreads();  // (B) all waves' PV reads of Vt done
      int nxt = cur ^ 1;
#pragma unroll
      for (int i = 0; i < 3; i++) *(s16x8*)&Kl[nxt][krow[i]][kco[i] * 8] = sk[i];
#pragma unroll
      for (int i = 0; i < 2; i++) *(s16x8*)&Vt[vd[i]][vco[i] * 8] = sv[i];
      if (v2) *(s16x8*)&Vt[vd[2]][vco[2] * 8] = sv[2];
    }
  }
  // epilogue: normalize by l, store d<72 at sigma-permuted column
#pragma unroll
  for (int g = 0; g < 2; g++)
#pragma unroll
    for (int r = 0; r < 4; r++) {
      float inv = 1.0f / __shfl(l_r[g], 4 * lq + r);
      int qrow = qrow0 + g * 16 + 4 * lq + r;
      size_t rowbase = (size_t)(t * 1024 + qrow) * 1152;
#pragma unroll
      for (int v = 0; v < 5; v++) {
        int d = v * 16 + l15;
        if (d < 72) {
          int col = h * 72 + d;
          int scol = (col & ~12) | ((col & 4) << 1) | ((col & 8) >> 1);
          att[rowbase + scol] = f2b(o[g][v][r] * inv);
        }
      }
    }
}

extern "C" void kernel_launch(void* const* d_in, const int* in_sizes, int n_in,
                              void* d_out, int out_size, void* d_ws, size_t ws_size,
                              hipStream_t stream) {
  const float* x   = (const float*)d_in[0];
  const float* Wq  = (const float*)d_in[1];
  const float* bq  = (const float*)d_in[2];
  const float* Wkv = (const float*)d_in[3];
  const float* bkv = (const float*)d_in[4];
  const float* qg  = (const float*)d_in[5];
  const float* kg  = (const float*)d_in[6];
  const float* Wo  = (const float*)d_in[7];
  float* out = (float*)d_out;

  char* w = (char*)d_ws;
  unsigned short* xb   = (unsigned short*)w; w += (size_t)8192 * 1152 * 2;
  unsigned short* WqT  = (unsigned short*)w; w += (size_t)1152 * 1152 * 2;  // contiguous with WkvT
  unsigned short* WkvT = (unsigned short*)w; w += (size_t)2304 * 1152 * 2;
  unsigned short* WoT  = (unsigned short*)w; w += (size_t)1152 * 1152 * 2;
  unsigned short* qn   = (unsigned short*)w; w += (size_t)128 * 1024 * 96 * 2;
  unsigned short* kn   = (unsigned short*)w; w += (size_t)128 * 1024 * 96 * 2;
  unsigned short* vt   = (unsigned short*)w; w += (size_t)128 * 80 * 1024 * 2;
  unsigned short* att  = (unsigned short*)w; w += (size_t)8192 * 1152 * 2;

  pre_kernel<<<7488, 256, 0, stream>>>(x, Wq, Wkv, Wo, xb, WqT, WkvT, WoT);

  // fused q,k,v^T GEMM: BT = [WqT ; WkvT] = [3456][1152], grid 32*27=864
  gemm_qkv_kernel<<<864, 256, 0, stream>>>(xb, WqT, bq, bkv, qn, kn, vt);
  rmsnorm_k_kernel<<<8192, 256, 0, stream>>>(kn, kg);

  attn_kernel<<<1024, 256, 0, stream>>>(qn, kn, vt, qg, att);

  // out = att @ WoT^T, grid 288 (256x128 blocks)
  gemm_out_kernel<<<288, 256, 0, stream>>>(att, WoT, out);
}